// Round 9
// baseline (692.679 us; speedup 1.0000x reference)
//
#include <hip/hip_runtime.h>

// EntityAwareAttention on MI355X (gfx950), bf16 MFMA pipeline.
// R12 = R11 + flash v9: V direct-to-register (vbuf deleted).
// Post-mortem R10/R11: pbuf-conflict fix changed nothing (counter identical
// 1.681e7) -- per-wave-op bank audit shows all LDS ops already at the b128
// minimum; conflicts are not the lever. The DS pipe IS: PV was reading
// 96 vbuf-b128 wave-ops/iter (~1350 cyc, m134) vs ~210 cyc MFMA issue.
// vf == Vt[d0+16dt][j*32+(lane>>4)*8..+8] exactly (layout algebra), a 16B
// coalesced global load (16 full 64B lines per wave-op), L2-hot. So:
//  - V(j) prefetched to 12 bf16x8 regs at iter start (2 phases of cover).
//  - (C) barrier: lgkm only; compiler auto-emits counted vmcnt for vreg
//    deps (K(j+1) stays in flight). Last-iter V race structurally gone
//    (register dep is hardware-tracked per wave).
//  - QK chain split: two accumulators (slo/shi), halves the 12-deep
//    MFMA32 dependency chain; +16 VALU adds.
// LDS 148.5 -> ~100 KB. VGPR ~190 (2 waves/SIMD kept).
// prep/gemm kernels unchanged from R11.

typedef short bf16x8 __attribute__((ext_vector_type(8)));
typedef float f32x4 __attribute__((ext_vector_type(4)));
typedef float f32x16 __attribute__((ext_vector_type(16)));

#define MFMA16(a, b, c) __builtin_amdgcn_mfma_f32_16x16x32_bf16(a, b, c, 0, 0, 0)
#define MFMA32(a, b, c) __builtin_amdgcn_mfma_f32_32x32x16_bf16(a, b, c, 0, 0, 0)

#define ASM_BAR() asm volatile("s_barrier" ::: "memory")
#define ASM_WAITV0() asm volatile("s_waitcnt vmcnt(0)" ::: "memory")
#define ASM_WAITV4() asm volatile("s_waitcnt vmcnt(4)" ::: "memory")
#define ASM_WAITL0() asm volatile("s_waitcnt lgkmcnt(0)" ::: "memory")

__device__ __forceinline__ unsigned short f2bf(float f) {
  unsigned u = __float_as_uint(f);
  u = u + 0x7FFFu + ((u >> 16) & 1u);  // RNE
  return (unsigned short)(u >> 16);
}

__device__ __forceinline__ void gll16(const void* g, void* l) {
  __builtin_amdgcn_global_load_lds(
      (const __attribute__((address_space(1))) unsigned int*)g,
      (__attribute__((address_space(3))) unsigned int*)l, 16, 0, 0);
}

// 1/sqrt(768) * log2(e): softmax computed as exp2((qk)*SCALE_L2E + kb*log2e)
#define SCALE_L2E 0.05205877316f
#define LOG2E 1.4426950408889634f

// ---------------- fused prep: hs->bf16, W->bf16, key-bias table ----------------
#define HS_BLOCKS 12288
#define W_BLOCKS 1728
#define KB_BLOCKS 64
__global__ void prep_kernel(const float* __restrict__ hs, unsigned short* __restrict__ ohs,
                            const float* __restrict__ w0, const float* __restrict__ w1,
                            const float* __restrict__ w2, unsigned short* __restrict__ o0,
                            unsigned short* __restrict__ o1, unsigned short* __restrict__ o2,
                            const float* __restrict__ mask, const int* __restrict__ ep,
                            float* __restrict__ kb) {
  __shared__ int eps[64];
  const int bid = blockIdx.x;
  const int t = threadIdx.x;
  if (bid < HS_BLOCKS) {
    const int i = (bid * 256 + t) * 4;
    float4 v = *(const float4*)(hs + i);
    *(ushort4*)(ohs + i) = make_ushort4(f2bf(v.x), f2bf(v.y), f2bf(v.z), f2bf(v.w));
  } else if (bid < HS_BLOCKS + W_BLOCKS) {
    const int wb = bid - HS_BLOCKS;
    const int which = wb / 576;
    const float* s = which == 0 ? w0 : (which == 1 ? w1 : w2);
    unsigned short* d = which == 0 ? o0 : (which == 1 ? o1 : o2);
    const int i = ((wb - which * 576) * 256 + t) * 4;
    float4 v = *(const float4*)(s + i);
    *(ushort4*)(d + i) = make_ushort4(f2bf(v.x), f2bf(v.y), f2bf(v.z), f2bf(v.w));
  } else {
    const int s = (bid - HS_BLOCKS - W_BLOCKS) * 256 + t;  // 0..16383
    const int b = s >> 12;                                 // block spans one batch
    if (t < 64) eps[t] = ep[b * 64 + t];
    __syncthreads();
    const int sp = s & 4095;
    float cnt = 0.0f;
#pragma unroll 8
    for (int e = 0; e < 64; e++) cnt += (eps[e] == sp) ? 1.0f : 0.0f;
    kb[s] = (1.0f - mask[s]) * (-10000.0f * LOG2E) + cnt * LOG2E;
  }
}

// ---------------- fused GEMM: Q,K = hs@W^T+b (bids 0..1535), V^T (1536..2303) --
// Both operands bf16, staged via global_load_lds; 3-stage counted-vmcnt
// pipeline (R9). Bodies unchanged; grid flattened into one launch.
__global__ __launch_bounds__(256, 3) void gemm_qkv_kernel(
    const unsigned short* __restrict__ hsb, const unsigned short* __restrict__ Wqb,
    const unsigned short* __restrict__ Wkb, const unsigned short* __restrict__ Wvb,
    const float* __restrict__ bq, const float* __restrict__ bk, const float* __restrict__ bv,
    unsigned short* __restrict__ Qb, unsigned short* __restrict__ Kb,
    unsigned short* __restrict__ Vt) {
  __shared__ __align__(16) unsigned short Ab[3][128 * 32];
  __shared__ __align__(16) unsigned short Bb[3][128 * 32];

  const int bid = blockIdx.x;
  const int t = threadIdx.x;
  const int lane = t & 63;
  const int w = t >> 6;
  const int wm = w & 1, wn = w >> 1;

  const bool is_vt = bid >= 1536;
  const unsigned short* srcA;
  const unsigned short* srcB;
  int m0, n0, z = 0;
  if (!is_vt) {
    z = bid / 768;
    const int r = bid - z * 768;
    m0 = (r & 127) * 128;        // r%128
    n0 = (r >> 7) * 128;         // r/128 in 0..5
    srcA = hsb;
    srcB = z ? Wkb : Wqb;
  } else {
    const int r = bid - 1536;
    const int mx = r % 6;
    m0 = mx * 128;               // o
    n0 = (r / 6) * 128;          // m = b*4096+s
    srcA = Wvb;
    srcB = hsb;
  }

  f32x4 acc[4][4] = {};

  auto issueT = [&](const unsigned short* src, int base, int kk, unsigned short* dst) {
#pragma unroll
    for (int r = 0; r < 2; r++) {
      int u = r * 256 + t;
      int o = u >> 2, cc = u & 3;
      int c = cc ^ ((o >> 1) & 3);
      gll16(src + (size_t)(base + o) * 768 + kk + c * 8, dst + u * 8);
    }
  };

  // prologue: stages 0 and 1 in flight; drain stage 0, keep stage 1.
  issueT(srcA, m0, 0, Ab[0]);
  issueT(srcB, n0, 0, Bb[0]);
  issueT(srcA, m0, 32, Ab[1]);
  issueT(srcB, n0, 32, Bb[1]);
  ASM_WAITV4();
  ASM_BAR();

  for (int k = 0; k < 24; k++) {
    const int buf = k % 3;
    if (k < 22) {
      const int nb = (k + 2) % 3;
      issueT(srcA, m0, (k + 2) * 32, Ab[nb]);
      issueT(srcB, n0, (k + 2) * 32, Bb[nb]);
    }
    bf16x8 af[4], bfr[4];
#pragma unroll
    for (int mt = 0; mt < 4; mt++) {
      int row = wm * 64 + mt * 16 + (lane & 15);
      int cc = (lane >> 4) ^ ((row >> 1) & 3);
      af[mt] = *(const bf16x8*)(&Ab[buf][row * 32 + cc * 8]);
    }
#pragma unroll
    for (int nt = 0; nt < 4; nt++) {
      int row = wn * 64 + nt * 16 + (lane & 15);
      int cc = (lane >> 4) ^ ((row >> 1) & 3);
      bfr[nt] = *(const bf16x8*)(&Bb[buf][row * 32 + cc * 8]);
    }
#pragma unroll
    for (int mt = 0; mt < 4; mt++)
#pragma unroll
      for (int nt = 0; nt < 4; nt++) acc[mt][nt] = MFMA16(af[mt], bfr[nt], acc[mt][nt]);
    // drain stage(k+1) (oldest 4), keep stage(k+2) in flight across barrier.
    if (k < 22) {
      ASM_WAITV4();
    } else {
      ASM_WAITV0();
    }
    ASM_BAR();
  }

  if (!is_vt) {
    const float* bias = z ? bk : bq;
    unsigned short* out = z ? Kb : Qb;
#pragma unroll
    for (int nt = 0; nt < 4; nt++) {
      int col = n0 + wn * 64 + nt * 16 + (lane & 15);
      float bv_ = bias[col];
#pragma unroll
      for (int mt = 0; mt < 4; mt++) {
#pragma unroll
        for (int i = 0; i < 4; i++) {
          int row = m0 + wm * 64 + mt * 16 + (lane >> 4) * 4 + i;
          out[(size_t)row * 768 + col] = f2bf(acc[mt][nt][i] + bv_);
        }
      }
    }
  } else {
#pragma unroll
    for (int mt = 0; mt < 4; mt++) {
#pragma unroll
      for (int i = 0; i < 4; i++) {
        int row_o = m0 + wm * 64 + mt * 16 + (lane >> 4) * 4 + i;
        float bb = bv[row_o];
#pragma unroll
        for (int nt = 0; nt < 4; nt++) {
          int mcol = n0 + wn * 64 + nt * 16 + (lane & 15);
          int bat = mcol >> 12, s = mcol & 4095;
          Vt[(size_t)bat * 768 * 4096 + (size_t)row_o * 4096 + s] = f2bf(acc[mt][nt][i] + bb);
        }
      }
    }
  }
}

// ---------------- flash attention (v9: V direct-to-register) ----------------
// 512 thr / 8 waves. QK: rg = w&1 (32 q-rows, 32x32 MFMA), hg = w>>1 (192-c
// slice). PV: mt2 = w&1 (2 row-tiles), dg = w>>1 (192-d quarter).
// V(j) prefetched into 12 bf16x8 regs at iter start, consumed at PV(j).
// Denominator: per-thread f32 register accumulation over j, single
// cross-column shuffle reduce after the loop -> st_l.
// Queue/iter: [loadVreg(j):12] -> QK -> sx -> lgkm,BAR(B) -> issueK(j+1):6
// -> softmax -> lgkm,BAR(C) -> PV (compiler vmcnt(6) for vreg) ->
// vmcnt(0)[K drained],BAR(A).
// LDS = kbuf 48 + sx 32 + pbuf 4 + kb_lds 16 ~ 100 KB.
__global__ __launch_bounds__(512, 2) void flash_kernel(const unsigned short* __restrict__ Qb,
                                                       const unsigned short* __restrict__ Kb,
                                                       const unsigned short* __restrict__ Vt,
                                                       const float* __restrict__ KB,
                                                       float* __restrict__ out) {
  __shared__ __align__(16) unsigned short kbuf[32 * 768];   // 48 KB
  __shared__ __align__(16) unsigned short pbuf[4 * 64 * 8]; // 4 KB
  __shared__ __align__(16) float sx[4 * 2 * 64 * 16];       // 32 KB, XOR-swizzled chunks
  __shared__ __align__(16) float kb_lds[4096];              // 16 KB
  __shared__ float st_l[64];

  const int t = threadIdx.x;
  const int lane = t & 63;
  const int w = t >> 6;
  const int rg = w & 1, hg = w >> 1;   // QK roles
  const int mt2 = w & 1, dg = w >> 1;  // PV roles
  const int flat = blockIdx.x;
  const int b = flat & 3, qt = flat >> 2;
  const int q0 = qt * 64;

  const unsigned short* Qg = Qb + (size_t)b * 4096 * 768;
  const unsigned short* Kg = Kb + (size_t)b * 4096 * 768;
  const unsigned short* Vg = Vt + (size_t)b * 768 * 4096;
  const float* KBb = KB + b * 4096;

  // Q A-frags for 32x32x16: row = lane&31, k = (lane>>5)*8 + 0..7
  bf16x8 qf[12];
  {
    const unsigned short* qp =
        Qg + (size_t)(q0 + rg * 32 + (lane & 31)) * 768 + hg * 192 + (lane >> 5) * 8;
#pragma unroll
    for (int c = 0; c < 12; c++) qf[c] = *(const bf16x8*)(qp + c * 16);
  }
  // KB preload into LDS (512 thr x 8 floats)
#pragma unroll
  for (int r = 0; r < 2; r++) {
    int i = t * 8 + r * 4;
    *(float4*)(kb_lds + i) = *(const float4*)(KBb + i);
  }

  // QK kbuf read offsets (shorts), loop-invariant.
  int kidx[12];
  {
    const int key = lane & 31, l5 = lane >> 5, sw = (key >> 1) & 3;
#pragma unroll
    for (int c = 0; c < 12; c++) {
      int g = hg * 24 + c * 2 + l5;
      kidx[c] = ((g >> 2) * 128 + key * 4 + ((g & 3) ^ sw)) * 8;
    }
  }
  // V direct-load base: vf(dt) == Vt[d0+16dt][j*32 + (lane>>4)*8 .. +8]
  const unsigned short* vptr =
      Vg + (size_t)(dg * 192 + (lane & 15)) * 4096 + (lane >> 4) * 8;
  // pbuf A-frag read offsets (perm: r ^ 2g ^ ((r>>2)&1))
  int pidx0, pidx1;
  {
    int g2 = lane >> 4;
    int r0 = mt2 * 32 + (lane & 15);
    int r1 = r0 + 16;
    pidx0 = (g2 * 64 + (r0 ^ (g2 * 2) ^ ((r0 >> 2) & 1))) * 8;
    pidx1 = (g2 * 64 + (r1 ^ (g2 * 2) ^ ((r1 >> 2) & 1))) * 8;
  }
  // softmax redistribution constants
  const int s_rg = t >> 8, s_q = (t >> 6) & 3, s_l = t & 63;
  const int col = s_l & 31;
  const int row_b = s_rg * 32 + 8 * s_q + 4 * (s_l >> 5);
  int pslot[4];
#pragma unroll
  for (int jj = 0; jj < 4; jj++) {
    int rw = row_b + jj;
    pslot[jj] = ((col >> 3) * 64 + (rw ^ ((col >> 3) * 2) ^ ((rw >> 2) & 1))) * 8 + (col & 7);
  }
  // sx: plane hg (2048 dwords), row r*16, chunk XOR-swizzled by (r>>1)&3
  float* sxw = sx + hg * 2048 + (rg * 64 + lane) * 16;
  const int wswz = (lane >> 1) & 3;
  const float* sxr = sx + (s_rg * 64 + s_l) * 16 + (s_q ^ ((s_l >> 1) & 3)) * 4;

  f32x4 oacc[24] = {};
  float racc0 = 0.0f, racc1 = 0.0f, racc2 = 0.0f, racc3 = 0.0f;  // f32 denom partials

  auto issueK = [&](int j) {
#pragma unroll
    for (int r = 0; r < 6; r++) {
      int u = r * 512 + t;
      int ks = u >> 7, rem = u & 127, key = rem >> 2, cs = rem & 3;
      int c = cs ^ ((key >> 1) & 3);
      gll16(Kg + (size_t)(j * 32 + key) * 768 + ks * 32 + c * 8, &kbuf[u * 8]);
    }
  };

  issueK(0);
  ASM_WAITV0();  // K(0) drained (ours); barrier makes all waves' K(0) visible
  ASM_BAR();

  for (int j = 0; j < 128; j++) {
    // entry: vmcnt queue empty; kbuf holds K(j), fully visible
    // ---- V(j) -> registers (consumed at PV(j); ~2 phases of latency cover) ----
    bf16x8 vreg[12];
#pragma unroll
    for (int dt = 0; dt < 12; dt++)
      vreg[dt] = *(const bf16x8*)(vptr + (size_t)dt * 16 * 4096 + j * 32);
    // ---- QK (split accumulators halve the dependency chain) ----
    f32x16 slo = {}, shi = {};
#pragma unroll
    for (int c = 0; c < 12; c += 2) {
      bf16x8 kf0 = *(const bf16x8*)(kbuf + kidx[c]);
      bf16x8 kf1 = *(const bf16x8*)(kbuf + kidx[c + 1]);
      slo = MFMA32(qf[c], kf0, slo);
      shi = MFMA32(qf[c + 1], kf1, shi);
    }
#pragma unroll
    for (int i = 0; i < 4; i++) {
      *(float4*)(sxw + (i ^ wswz) * 4) =
          make_float4(slo[i * 4] + shi[i * 4], slo[i * 4 + 1] + shi[i * 4 + 1],
                      slo[i * 4 + 2] + shi[i * 4 + 2], slo[i * 4 + 3] + shi[i * 4 + 3]);
    }
    ASM_WAITL0();
    ASM_BAR();  // (B): sx visible; kbuf reads done by all waves
    if (j < 127) issueK(j + 1);  // queue [V(j):12 (regs), K(j+1):6]
    // ---- softmax: 512 threads x 4 elements, exp2, reg-accumulated denom ----
    {
      float4 a0 = *(const float4*)(sxr);
      float4 a1 = *(const float4*)(sxr + 2048);
      float4 a2 = *(const float4*)(sxr + 4096);
      float4 a3 = *(const float4*)(sxr + 6144);
      float kbias = kb_lds[j * 32 + col];
      float e0 = __builtin_amdgcn_exp2f(fmaf(a0.x + a1.x + a2.x + a3.x, SCALE_L2E, kbias));
      float e1 = __builtin_amdgcn_exp2f(fmaf(a0.y + a1.y + a2.y + a3.y, SCALE_L2E, kbias));
      float e2 = __builtin_amdgcn_exp2f(fmaf(a0.z + a1.z + a2.z + a3.z, SCALE_L2E, kbias));
      float e3 = __builtin_amdgcn_exp2f(fmaf(a0.w + a1.w + a2.w + a3.w, SCALE_L2E, kbias));
      pbuf[pslot[0]] = f2bf(e0);
      pbuf[pslot[1]] = f2bf(e1);
      pbuf[pslot[2]] = f2bf(e2);
      pbuf[pslot[3]] = f2bf(e3);
      racc0 += e0;
      racc1 += e1;
      racc2 += e2;
      racc3 += e3;
    }
    ASM_WAITL0();
    ASM_BAR();  // (C): pbuf visible. V is a register dep (HW-tracked);
                // compiler emits the counted vmcnt before PV, K(j+1) stays
                // in flight. No last-iter special case needed.
    // ---- PV ----
    {
      bf16x8 pf0 = *(const bf16x8*)(pbuf + pidx0);
      bf16x8 pf1 = *(const bf16x8*)(pbuf + pidx1);
#pragma unroll
      for (int dt = 0; dt < 12; dt++) {
        oacc[dt] = MFMA16(pf0, vreg[dt], oacc[dt]);
        oacc[12 + dt] = MFMA16(pf1, vreg[dt], oacc[12 + dt]);
      }
    }
    ASM_WAITV0();  // K(j+1) drained (ours)
    ASM_BAR();     // (A): all waves' K(j+1) visible; pbuf reads done
  }
  // ---- final denominator reduction (once): sum racc across 32 cols ----
#pragma unroll
  for (int m = 1; m < 32; m <<= 1) {
    racc0 += __shfl_xor(racc0, m, 32);
    racc1 += __shfl_xor(racc1, m, 32);
    racc2 += __shfl_xor(racc2, m, 32);
    racc3 += __shfl_xor(racc3, m, 32);
  }
  if ((s_l & 31) == 0) {
    st_l[row_b] = racc0;
    st_l[row_b + 1] = racc1;
    st_l[row_b + 2] = racc2;
    st_l[row_b + 3] = racc3;
  }
  __syncthreads();
  // ---- epilogue ----
#pragma unroll
  for (int pt = 0; pt < 2; pt++) {
    int rb = mt2 * 32 + pt * 16 + (lane >> 4) * 4;
    float l0 = 1.0f / st_l[rb], l1 = 1.0f / st_l[rb + 1];
    float l2 = 1.0f / st_l[rb + 2], l3 = 1.0f / st_l[rb + 3];
#pragma unroll
    for (int dt = 0; dt < 12; dt++) {
      int d = dg * 192 + dt * 16 + (lane & 15);
      size_t base = ((size_t)(b * 4096 + q0 + rb)) * 768 + d;
      out[base] = oacc[pt * 12 + dt][0] * l0;
      out[base + 768] = oacc[pt * 12 + dt][1] * l1;
      out[base + 2 * 768] = oacc[pt * 12 + dt][2] * l2;
      out[base + 3 * 768] = oacc[pt * 12 + dt][3] * l3;
    }
  }
}

extern "C" void kernel_launch(void* const* d_in, const int* in_sizes, int n_in, void* d_out,
                              int out_size, void* d_ws, size_t ws_size, hipStream_t stream) {
  const float* hs = (const float*)d_in[0];
  const float* mask = (const float*)d_in[1];
  const int* ep = (const int*)d_in[2];
  const float* Wq = (const float*)d_in[3];
  const float* bq = (const float*)d_in[4];
  const float* Wk = (const float*)d_in[5];
  const float* bk = (const float*)d_in[6];
  const float* Wv = (const float*)d_in[7];
  const float* bv = (const float*)d_in[8];
  float* outp = (float*)d_out;

  char* ws = (char*)d_ws;
  unsigned short* Qb = (unsigned short*)(ws);
  unsigned short* Kb = (unsigned short*)(ws + 25165824);
  unsigned short* Vt = (unsigned short*)(ws + 50331648);
  unsigned short* Wqb = (unsigned short*)(ws + 75497472);
  unsigned short* Wkb = (unsigned short*)(ws + 76677120);
  unsigned short* Wvb = (unsigned short*)(ws + 77856768);
  float* KBp = (float*)(ws + 79036416);
  unsigned short* Hsb = (unsigned short*)(ws + 79101952);  // 16384x768 bf16, 24 MB

  prep_kernel<<<HS_BLOCKS + W_BLOCKS + KB_BLOCKS, 256, 0, stream>>>(
      hs, Hsb, Wq, Wk, Wv, Wqb, Wkb, Wvb, mask, ep, KBp);
  gemm_qkv_kernel<<<2304, 256, 0, stream>>>(Hsb, Wqb, Wkb, Wvb, bq, bk, bv, Qb, Kb, Vt);
  flash_kernel<<<256, 512, 0, stream>>>(Qb, Kb, Vt, KBp, outp);
}

// Round 10
// 501.266 us; speedup vs baseline: 1.3819x; 1.3819x over previous
//
#include <hip/hip_runtime.h>

// EntityAwareAttention on MI355X (gfx950), bf16 MFMA pipeline.
// R13 = R11 flash restored (vbuf LDS staging back) + R12's split QK
// accumulator (the one R12 piece that was independently verified).
// R12 post-mortem: V direct-to-register needed ~224 live VGPRs; compiler
// allocated 128 and rematerialized the V loads at their PV use sites ->
// 12 latency-exposed L2 loads/iter (+2-3k cyc) + 16-line scatter per load
// (1536 line-transactions/iter/CU vs 96 staged). LDS staging is correct.
// Flash queue discipline (R7-verified):
//   [entry: queue empty] issueV(j):6 -> QK -> sx -> lgkm,BAR(B)
//   -> issueK(j+1):6 -> softmax -> lgkm,vmcnt(6|0),BAR(C)
//   -> PV -> vmcnt(0)[K drained],BAR(A)
// prep/gemm kernels unchanged from R11 (fused, 3 launches total).

typedef short bf16x8 __attribute__((ext_vector_type(8)));
typedef float f32x4 __attribute__((ext_vector_type(4)));
typedef float f32x16 __attribute__((ext_vector_type(16)));

#define MFMA16(a, b, c) __builtin_amdgcn_mfma_f32_16x16x32_bf16(a, b, c, 0, 0, 0)
#define MFMA32(a, b, c) __builtin_amdgcn_mfma_f32_32x32x16_bf16(a, b, c, 0, 0, 0)

#define ASM_BAR() asm volatile("s_barrier" ::: "memory")
#define ASM_WAITV0() asm volatile("s_waitcnt vmcnt(0)" ::: "memory")
#define ASM_WAITV4() asm volatile("s_waitcnt vmcnt(4)" ::: "memory")
#define ASM_WAITV6() asm volatile("s_waitcnt vmcnt(6)" ::: "memory")
#define ASM_WAITL0() asm volatile("s_waitcnt lgkmcnt(0)" ::: "memory")

__device__ __forceinline__ unsigned short f2bf(float f) {
  unsigned u = __float_as_uint(f);
  u = u + 0x7FFFu + ((u >> 16) & 1u);  // RNE
  return (unsigned short)(u >> 16);
}

__device__ __forceinline__ void gll16(const void* g, void* l) {
  __builtin_amdgcn_global_load_lds(
      (const __attribute__((address_space(1))) unsigned int*)g,
      (__attribute__((address_space(3))) unsigned int*)l, 16, 0, 0);
}

// 1/sqrt(768) * log2(e): softmax computed as exp2((qk)*SCALE_L2E + kb*log2e)
#define SCALE_L2E 0.05205877316f
#define LOG2E 1.4426950408889634f

// ---------------- fused prep: hs->bf16, W->bf16, key-bias table ----------------
#define HS_BLOCKS 12288
#define W_BLOCKS 1728
#define KB_BLOCKS 64
__global__ void prep_kernel(const float* __restrict__ hs, unsigned short* __restrict__ ohs,
                            const float* __restrict__ w0, const float* __restrict__ w1,
                            const float* __restrict__ w2, unsigned short* __restrict__ o0,
                            unsigned short* __restrict__ o1, unsigned short* __restrict__ o2,
                            const float* __restrict__ mask, const int* __restrict__ ep,
                            float* __restrict__ kb) {
  __shared__ int eps[64];
  const int bid = blockIdx.x;
  const int t = threadIdx.x;
  if (bid < HS_BLOCKS) {
    const int i = (bid * 256 + t) * 4;
    float4 v = *(const float4*)(hs + i);
    *(ushort4*)(ohs + i) = make_ushort4(f2bf(v.x), f2bf(v.y), f2bf(v.z), f2bf(v.w));
  } else if (bid < HS_BLOCKS + W_BLOCKS) {
    const int wb = bid - HS_BLOCKS;
    const int which = wb / 576;
    const float* s = which == 0 ? w0 : (which == 1 ? w1 : w2);
    unsigned short* d = which == 0 ? o0 : (which == 1 ? o1 : o2);
    const int i = ((wb - which * 576) * 256 + t) * 4;
    float4 v = *(const float4*)(s + i);
    *(ushort4*)(d + i) = make_ushort4(f2bf(v.x), f2bf(v.y), f2bf(v.z), f2bf(v.w));
  } else {
    const int s = (bid - HS_BLOCKS - W_BLOCKS) * 256 + t;  // 0..16383
    const int b = s >> 12;                                 // block spans one batch
    if (t < 64) eps[t] = ep[b * 64 + t];
    __syncthreads();
    const int sp = s & 4095;
    float cnt = 0.0f;
#pragma unroll 8
    for (int e = 0; e < 64; e++) cnt += (eps[e] == sp) ? 1.0f : 0.0f;
    kb[s] = (1.0f - mask[s]) * (-10000.0f * LOG2E) + cnt * LOG2E;
  }
}

// ---------------- fused GEMM: Q,K = hs@W^T+b (bids 0..1535), V^T (1536..2303) --
__global__ __launch_bounds__(256, 3) void gemm_qkv_kernel(
    const unsigned short* __restrict__ hsb, const unsigned short* __restrict__ Wqb,
    const unsigned short* __restrict__ Wkb, const unsigned short* __restrict__ Wvb,
    const float* __restrict__ bq, const float* __restrict__ bk, const float* __restrict__ bv,
    unsigned short* __restrict__ Qb, unsigned short* __restrict__ Kb,
    unsigned short* __restrict__ Vt) {
  __shared__ __align__(16) unsigned short Ab[3][128 * 32];
  __shared__ __align__(16) unsigned short Bb[3][128 * 32];

  const int bid = blockIdx.x;
  const int t = threadIdx.x;
  const int lane = t & 63;
  const int w = t >> 6;
  const int wm = w & 1, wn = w >> 1;

  const bool is_vt = bid >= 1536;
  const unsigned short* srcA;
  const unsigned short* srcB;
  int m0, n0, z = 0;
  if (!is_vt) {
    z = bid / 768;
    const int r = bid - z * 768;
    m0 = (r & 127) * 128;        // r%128
    n0 = (r >> 7) * 128;         // r/128 in 0..5
    srcA = hsb;
    srcB = z ? Wkb : Wqb;
  } else {
    const int r = bid - 1536;
    const int mx = r % 6;
    m0 = mx * 128;               // o
    n0 = (r / 6) * 128;          // m = b*4096+s
    srcA = Wvb;
    srcB = hsb;
  }

  f32x4 acc[4][4] = {};

  auto issueT = [&](const unsigned short* src, int base, int kk, unsigned short* dst) {
#pragma unroll
    for (int r = 0; r < 2; r++) {
      int u = r * 256 + t;
      int o = u >> 2, cc = u & 3;
      int c = cc ^ ((o >> 1) & 3);
      gll16(src + (size_t)(base + o) * 768 + kk + c * 8, dst + u * 8);
    }
  };

  // prologue: stages 0 and 1 in flight; drain stage 0, keep stage 1.
  issueT(srcA, m0, 0, Ab[0]);
  issueT(srcB, n0, 0, Bb[0]);
  issueT(srcA, m0, 32, Ab[1]);
  issueT(srcB, n0, 32, Bb[1]);
  ASM_WAITV4();
  ASM_BAR();

  for (int k = 0; k < 24; k++) {
    const int buf = k % 3;
    if (k < 22) {
      const int nb = (k + 2) % 3;
      issueT(srcA, m0, (k + 2) * 32, Ab[nb]);
      issueT(srcB, n0, (k + 2) * 32, Bb[nb]);
    }
    bf16x8 af[4], bfr[4];
#pragma unroll
    for (int mt = 0; mt < 4; mt++) {
      int row = wm * 64 + mt * 16 + (lane & 15);
      int cc = (lane >> 4) ^ ((row >> 1) & 3);
      af[mt] = *(const bf16x8*)(&Ab[buf][row * 32 + cc * 8]);
    }
#pragma unroll
    for (int nt = 0; nt < 4; nt++) {
      int row = wn * 64 + nt * 16 + (lane & 15);
      int cc = (lane >> 4) ^ ((row >> 1) & 3);
      bfr[nt] = *(const bf16x8*)(&Bb[buf][row * 32 + cc * 8]);
    }
#pragma unroll
    for (int mt = 0; mt < 4; mt++)
#pragma unroll
      for (int nt = 0; nt < 4; nt++) acc[mt][nt] = MFMA16(af[mt], bfr[nt], acc[mt][nt]);
    // drain stage(k+1) (oldest 4), keep stage(k+2) in flight across barrier.
    if (k < 22) {
      ASM_WAITV4();
    } else {
      ASM_WAITV0();
    }
    ASM_BAR();
  }

  if (!is_vt) {
    const float* bias = z ? bk : bq;
    unsigned short* out = z ? Kb : Qb;
#pragma unroll
    for (int nt = 0; nt < 4; nt++) {
      int col = n0 + wn * 64 + nt * 16 + (lane & 15);
      float bv_ = bias[col];
#pragma unroll
      for (int mt = 0; mt < 4; mt++) {
#pragma unroll
        for (int i = 0; i < 4; i++) {
          int row = m0 + wm * 64 + mt * 16 + (lane >> 4) * 4 + i;
          out[(size_t)row * 768 + col] = f2bf(acc[mt][nt][i] + bv_);
        }
      }
    }
  } else {
#pragma unroll
    for (int mt = 0; mt < 4; mt++) {
#pragma unroll
      for (int i = 0; i < 4; i++) {
        int row_o = m0 + wm * 64 + mt * 16 + (lane >> 4) * 4 + i;
        float bb = bv[row_o];
#pragma unroll
        for (int nt = 0; nt < 4; nt++) {
          int mcol = n0 + wn * 64 + nt * 16 + (lane & 15);
          int bat = mcol >> 12, s = mcol & 4095;
          Vt[(size_t)bat * 768 * 4096 + (size_t)row_o * 4096 + s] = f2bf(acc[mt][nt][i] + bb);
        }
      }
    }
  }
}

// ---------------- flash attention (v10 = v8 + split QK accumulator) ----------------
// 512 thr / 8 waves. QK: rg = w&1 (32 q-rows, 32x32 MFMA), hg = w>>1 (192-c
// slice). PV: mt2 = w&1 (2 row-tiles), dg = w>>1 (192-d quarter).
// Denominator: per-thread f32 register accumulation over j, single
// cross-column shuffle reduce after the loop -> st_l.
// QK uses two accumulators (slo/shi) to halve the 12-deep MFMA32 chain
// (verified correct in R12: passed, absmax identical).
// LDS = kbuf 48 + vbuf 48 + sx 32 + pbuf 4 + kb_lds 16 ~ 148 KB.
__global__ __launch_bounds__(512, 2) void flash_kernel(const unsigned short* __restrict__ Qb,
                                                       const unsigned short* __restrict__ Kb,
                                                       const unsigned short* __restrict__ Vt,
                                                       const float* __restrict__ KB,
                                                       float* __restrict__ out) {
  __shared__ __align__(16) unsigned short kbuf[32 * 768];   // 48 KB
  __shared__ __align__(16) unsigned short vbuf[768 * 32];   // 48 KB
  __shared__ __align__(16) unsigned short pbuf[4 * 64 * 8]; // 4 KB
  __shared__ __align__(16) float sx[4 * 2 * 64 * 16];       // 32 KB, XOR-swizzled chunks
  __shared__ __align__(16) float kb_lds[4096];              // 16 KB
  __shared__ float st_l[64];

  const int t = threadIdx.x;
  const int lane = t & 63;
  const int w = t >> 6;
  const int rg = w & 1, hg = w >> 1;   // QK roles
  const int mt2 = w & 1, dg = w >> 1;  // PV roles
  const int flat = blockIdx.x;
  const int b = flat & 3, qt = flat >> 2;
  const int q0 = qt * 64;

  const unsigned short* Qg = Qb + (size_t)b * 4096 * 768;
  const unsigned short* Kg = Kb + (size_t)b * 4096 * 768;
  const unsigned short* Vg = Vt + (size_t)b * 768 * 4096;
  const float* KBb = KB + b * 4096;

  // Q A-frags for 32x32x16: row = lane&31, k = (lane>>5)*8 + 0..7
  bf16x8 qf[12];
  {
    const unsigned short* qp =
        Qg + (size_t)(q0 + rg * 32 + (lane & 31)) * 768 + hg * 192 + (lane >> 5) * 8;
#pragma unroll
    for (int c = 0; c < 12; c++) qf[c] = *(const bf16x8*)(qp + c * 16);
  }
  // KB preload into LDS (512 thr x 8 floats)
#pragma unroll
  for (int r = 0; r < 2; r++) {
    int i = t * 8 + r * 4;
    *(float4*)(kb_lds + i) = *(const float4*)(KBb + i);
  }

  // QK kbuf read offsets (shorts), loop-invariant.
  int kidx[12];
  {
    const int key = lane & 31, l5 = lane >> 5, sw = (key >> 1) & 3;
#pragma unroll
    for (int c = 0; c < 12; c++) {
      int g = hg * 24 + c * 2 + l5;
      kidx[c] = ((g >> 2) * 128 + key * 4 + ((g & 3) ^ sw)) * 8;
    }
  }
  // PV vbuf base
  int vbase;
  {
    int d0 = dg * 192 + (lane & 15);
    vbase = (d0 * 4 + ((lane >> 4) ^ ((d0 >> 1) & 3))) * 8;
  }
  // pbuf A-frag read offsets (perm: r ^ 2g ^ ((r>>2)&1))
  int pidx0, pidx1;
  {
    int g2 = lane >> 4;
    int r0 = mt2 * 32 + (lane & 15);
    int r1 = r0 + 16;
    pidx0 = (g2 * 64 + (r0 ^ (g2 * 2) ^ ((r0 >> 2) & 1))) * 8;
    pidx1 = (g2 * 64 + (r1 ^ (g2 * 2) ^ ((r1 >> 2) & 1))) * 8;
  }
  // softmax redistribution constants
  const int s_rg = t >> 8, s_q = (t >> 6) & 3, s_l = t & 63;
  const int col = s_l & 31;
  const int row_b = s_rg * 32 + 8 * s_q + 4 * (s_l >> 5);
  int pslot[4];
#pragma unroll
  for (int jj = 0; jj < 4; jj++) {
    int rw = row_b + jj;
    pslot[jj] = ((col >> 3) * 64 + (rw ^ ((col >> 3) * 2) ^ ((rw >> 2) & 1))) * 8 + (col & 7);
  }
  // sx: plane hg (2048 dwords), row r*16, chunk XOR-swizzled by (r>>1)&3
  float* sxw = sx + hg * 2048 + (rg * 64 + lane) * 16;
  const int wswz = (lane >> 1) & 3;
  const float* sxr = sx + (s_rg * 64 + s_l) * 16 + (s_q ^ ((s_l >> 1) & 3)) * 4;

  f32x4 oacc[24] = {};
  float racc0 = 0.0f, racc1 = 0.0f, racc2 = 0.0f, racc3 = 0.0f;  // f32 denom partials

  auto issueK = [&](int j) {
#pragma unroll
    for (int r = 0; r < 6; r++) {
      int u = r * 512 + t;
      int ks = u >> 7, rem = u & 127, key = rem >> 2, cs = rem & 3;
      int c = cs ^ ((key >> 1) & 3);
      gll16(Kg + (size_t)(j * 32 + key) * 768 + ks * 32 + c * 8, &kbuf[u * 8]);
    }
  };
  auto issueV = [&](int j) {
#pragma unroll
    for (int r = 0; r < 6; r++) {
      int u = r * 512 + t;
      int d = u >> 2, cs = u & 3;
      int c = cs ^ ((d >> 1) & 3);
      gll16(Vg + (size_t)d * 4096 + j * 32 + c * 8, &vbuf[u * 8]);
    }
  };

  issueK(0);
  ASM_WAITV0();  // K(0) drained (ours); barrier makes all waves' K(0) visible
  ASM_BAR();

  for (int j = 0; j < 128; j++) {
    // entry: queue empty; kbuf holds K(j), fully visible
    issueV(j);  // queue [V(j):6]; vbuf free (all waves past PV(j-1) drain at (A))
    // ---- QK (split accumulators halve the dependency chain) ----
    f32x16 slo = {}, shi = {};
#pragma unroll
    for (int c = 0; c < 12; c += 2) {
      bf16x8 kf0 = *(const bf16x8*)(kbuf + kidx[c]);
      bf16x8 kf1 = *(const bf16x8*)(kbuf + kidx[c + 1]);
      slo = MFMA32(qf[c], kf0, slo);
      shi = MFMA32(qf[c + 1], kf1, shi);
    }
#pragma unroll
    for (int i = 0; i < 4; i++) {
      *(float4*)(sxw + (i ^ wswz) * 4) =
          make_float4(slo[i * 4] + shi[i * 4], slo[i * 4 + 1] + shi[i * 4 + 1],
                      slo[i * 4 + 2] + shi[i * 4 + 2], slo[i * 4 + 3] + shi[i * 4 + 3]);
    }
    ASM_WAITL0();
    ASM_BAR();  // (B): sx visible; kbuf reads done by all waves
    if (j < 127) issueK(j + 1);  // queue [V(j):6, K(j+1):6]
    // ---- softmax: 512 threads x 4 elements, exp2, reg-accumulated denom ----
    {
      float4 a0 = *(const float4*)(sxr);
      float4 a1 = *(const float4*)(sxr + 2048);
      float4 a2 = *(const float4*)(sxr + 4096);
      float4 a3 = *(const float4*)(sxr + 6144);
      float kbias = kb_lds[j * 32 + col];
      float e0 = __builtin_amdgcn_exp2f(fmaf(a0.x + a1.x + a2.x + a3.x, SCALE_L2E, kbias));
      float e1 = __builtin_amdgcn_exp2f(fmaf(a0.y + a1.y + a2.y + a3.y, SCALE_L2E, kbias));
      float e2 = __builtin_amdgcn_exp2f(fmaf(a0.z + a1.z + a2.z + a3.z, SCALE_L2E, kbias));
      float e3 = __builtin_amdgcn_exp2f(fmaf(a0.w + a1.w + a2.w + a3.w, SCALE_L2E, kbias));
      pbuf[pslot[0]] = f2bf(e0);
      pbuf[pslot[1]] = f2bf(e1);
      pbuf[pslot[2]] = f2bf(e2);
      pbuf[pslot[3]] = f2bf(e3);
      racc0 += e0;
      racc1 += e1;
      racc2 += e2;
      racc3 += e3;
    }
    ASM_WAITL0();
    // (C) drain: normal iters have queue [V(j):6, K(j+1):6] -> vmcnt(6)
    // drains V. Final iter has only [V(127):6] -> must drain fully.
    if (j < 127) {
      ASM_WAITV6();
    } else {
      ASM_WAITV0();
    }
    ASM_BAR();     // (C): pbuf visible; all waves' V(j) drained -> vbuf valid
    // ---- PV ----
    {
      bf16x8 pf0 = *(const bf16x8*)(pbuf + pidx0);
      bf16x8 pf1 = *(const bf16x8*)(pbuf + pidx1);
#pragma unroll
      for (int dt = 0; dt < 12; dt++) {
        bf16x8 vf = *(const bf16x8*)(vbuf + vbase + dt * 512);
        oacc[dt] = MFMA16(pf0, vf, oacc[dt]);
        oacc[12 + dt] = MFMA16(pf1, vf, oacc[12 + dt]);
      }
    }
    ASM_WAITV0();  // K(j+1) drained (ours)
    ASM_BAR();     // (A): all waves' K(j+1) visible; vbuf/pbuf reads done
  }
  // ---- final denominator reduction (once): sum racc across 32 cols ----
#pragma unroll
  for (int m = 1; m < 32; m <<= 1) {
    racc0 += __shfl_xor(racc0, m, 32);
    racc1 += __shfl_xor(racc1, m, 32);
    racc2 += __shfl_xor(racc2, m, 32);
    racc3 += __shfl_xor(racc3, m, 32);
  }
  if ((s_l & 31) == 0) {
    st_l[row_b] = racc0;
    st_l[row_b + 1] = racc1;
    st_l[row_b + 2] = racc2;
    st_l[row_b + 3] = racc3;
  }
  __syncthreads();
  // ---- epilogue ----
#pragma unroll
  for (int pt = 0; pt < 2; pt++) {
    int rb = mt2 * 32 + pt * 16 + (lane >> 4) * 4;
    float l0 = 1.0f / st_l[rb], l1 = 1.0f / st_l[rb + 1];
    float l2 = 1.0f / st_l[rb + 2], l3 = 1.0f / st_l[rb + 3];
#pragma unroll
    for (int dt = 0; dt < 12; dt++) {
      int d = dg * 192 + dt * 16 + (lane & 15);
      size_t base = ((size_t)(b * 4096 + q0 + rb)) * 768 + d;
      out[base] = oacc[pt * 12 + dt][0] * l0;
      out[base + 768] = oacc[pt * 12 + dt][1] * l1;
      out[base + 2 * 768] = oacc[pt * 12 + dt][2] * l2;
      out[base + 3 * 768] = oacc[pt * 12 + dt][3] * l3;
    }
  }
}

extern "C" void kernel_launch(void* const* d_in, const int* in_sizes, int n_in, void* d_out,
                              int out_size, void* d_ws, size_t ws_size, hipStream_t stream) {
  const float* hs = (const float*)d_in[0];
  const float* mask = (const float*)d_in[1];
  const int* ep = (const int*)d_in[2];
  const float* Wq = (const float*)d_in[3];
  const float* bq = (const float*)d_in[4];
  const float* Wk = (const float*)d_in[5];
  const float* bk = (const float*)d_in[6];
  const float* Wv = (const float*)d_in[7];
  const float* bv = (const float*)d_in[8];
  float* outp = (float*)d_out;

  char* ws = (char*)d_ws;
  unsigned short* Qb = (unsigned short*)(ws);
  unsigned short* Kb = (unsigned short*)(ws + 25165824);
  unsigned short* Vt = (unsigned short*)(ws + 50331648);
  unsigned short* Wqb = (unsigned short*)(ws + 75497472);
  unsigned short* Wkb = (unsigned short*)(ws + 76677120);
  unsigned short* Wvb = (unsigned short*)(ws + 77856768);
  float* KBp = (float*)(ws + 79036416);
  unsigned short* Hsb = (unsigned short*)(ws + 79101952);  // 16384x768 bf16, 24 MB

  prep_kernel<<<HS_BLOCKS + W_BLOCKS + KB_BLOCKS, 256, 0, stream>>>(
      hs, Hsb, Wq, Wk, Wv, Wqb, Wkb, Wvb, mask, ep, KBp);
  gemm_qkv_kernel<<<2304, 256, 0, stream>>>(Hsb, Wqb, Wkb, Wvb, bq, bk, bv, Qb, Kb, Vt);
  flash_kernel<<<256, 512, 0, stream>>>(Qb, Kb, Vt, KBp, outp);
}

// Round 11
// 478.330 us; speedup vs baseline: 1.4481x; 1.0479x over previous
//
#include <hip/hip_runtime.h>

// EntityAwareAttention on MI355X (gfx950), bf16 MFMA pipeline.
// R14 = exact R11 revert (verified 477.2 us).
// R13 post-mortem: split QK accumulator regressed flash 322->345 us
// (VGPR 124->128, MfmaUtil 27.9->25.2): +16 live VGPRs through QK plus 16
// dependent adds between last MFMA and the sx store lengthened the
// pre-BAR(B) critical path every wave serializes on. Its "verification" in
// R12 was correctness-only (R12's perf was dominated by reg-pressure
// rematerialization). Reverted to the single-accumulator QK.
// Structure ledger: R9 gemm 3-stage pipeline (neutral, kept), R10 pbuf
// swizzle (no counter change, kept harmlessly), R12 V-to-reg (-72%,
// reverted), R13 split acc (-7%, reverted here).
// Flash queue discipline per wave/iter (R7-verified):
//   [entry: queue empty] issueV(j):6 -> QK -> sx -> lgkm,BAR(B)
//   -> issueK(j+1):6 -> softmax (+4 reg adds) -> lgkm,vmcnt(6|0),BAR(C)
//   -> PV -> vmcnt(0)[K drained],BAR(A)

typedef short bf16x8 __attribute__((ext_vector_type(8)));
typedef float f32x4 __attribute__((ext_vector_type(4)));
typedef float f32x16 __attribute__((ext_vector_type(16)));

#define MFMA16(a, b, c) __builtin_amdgcn_mfma_f32_16x16x32_bf16(a, b, c, 0, 0, 0)
#define MFMA32(a, b, c) __builtin_amdgcn_mfma_f32_32x32x16_bf16(a, b, c, 0, 0, 0)

#define ASM_BAR() asm volatile("s_barrier" ::: "memory")
#define ASM_WAITV0() asm volatile("s_waitcnt vmcnt(0)" ::: "memory")
#define ASM_WAITV4() asm volatile("s_waitcnt vmcnt(4)" ::: "memory")
#define ASM_WAITV6() asm volatile("s_waitcnt vmcnt(6)" ::: "memory")
#define ASM_WAITL0() asm volatile("s_waitcnt lgkmcnt(0)" ::: "memory")

__device__ __forceinline__ unsigned short f2bf(float f) {
  unsigned u = __float_as_uint(f);
  u = u + 0x7FFFu + ((u >> 16) & 1u);  // RNE
  return (unsigned short)(u >> 16);
}

__device__ __forceinline__ void gll16(const void* g, void* l) {
  __builtin_amdgcn_global_load_lds(
      (const __attribute__((address_space(1))) unsigned int*)g,
      (__attribute__((address_space(3))) unsigned int*)l, 16, 0, 0);
}

// 1/sqrt(768) * log2(e): softmax computed as exp2((qk)*SCALE_L2E + kb*log2e)
#define SCALE_L2E 0.05205877316f
#define LOG2E 1.4426950408889634f

// ---------------- fused prep: hs->bf16, W->bf16, key-bias table ----------------
#define HS_BLOCKS 12288
#define W_BLOCKS 1728
#define KB_BLOCKS 64
__global__ void prep_kernel(const float* __restrict__ hs, unsigned short* __restrict__ ohs,
                            const float* __restrict__ w0, const float* __restrict__ w1,
                            const float* __restrict__ w2, unsigned short* __restrict__ o0,
                            unsigned short* __restrict__ o1, unsigned short* __restrict__ o2,
                            const float* __restrict__ mask, const int* __restrict__ ep,
                            float* __restrict__ kb) {
  __shared__ int eps[64];
  const int bid = blockIdx.x;
  const int t = threadIdx.x;
  if (bid < HS_BLOCKS) {
    const int i = (bid * 256 + t) * 4;
    float4 v = *(const float4*)(hs + i);
    *(ushort4*)(ohs + i) = make_ushort4(f2bf(v.x), f2bf(v.y), f2bf(v.z), f2bf(v.w));
  } else if (bid < HS_BLOCKS + W_BLOCKS) {
    const int wb = bid - HS_BLOCKS;
    const int which = wb / 576;
    const float* s = which == 0 ? w0 : (which == 1 ? w1 : w2);
    unsigned short* d = which == 0 ? o0 : (which == 1 ? o1 : o2);
    const int i = ((wb - which * 576) * 256 + t) * 4;
    float4 v = *(const float4*)(s + i);
    *(ushort4*)(d + i) = make_ushort4(f2bf(v.x), f2bf(v.y), f2bf(v.z), f2bf(v.w));
  } else {
    const int s = (bid - HS_BLOCKS - W_BLOCKS) * 256 + t;  // 0..16383
    const int b = s >> 12;                                 // block spans one batch
    if (t < 64) eps[t] = ep[b * 64 + t];
    __syncthreads();
    const int sp = s & 4095;
    float cnt = 0.0f;
#pragma unroll 8
    for (int e = 0; e < 64; e++) cnt += (eps[e] == sp) ? 1.0f : 0.0f;
    kb[s] = (1.0f - mask[s]) * (-10000.0f * LOG2E) + cnt * LOG2E;
  }
}

// ---------------- fused GEMM: Q,K = hs@W^T+b (bids 0..1535), V^T (1536..2303) --
__global__ __launch_bounds__(256, 3) void gemm_qkv_kernel(
    const unsigned short* __restrict__ hsb, const unsigned short* __restrict__ Wqb,
    const unsigned short* __restrict__ Wkb, const unsigned short* __restrict__ Wvb,
    const float* __restrict__ bq, const float* __restrict__ bk, const float* __restrict__ bv,
    unsigned short* __restrict__ Qb, unsigned short* __restrict__ Kb,
    unsigned short* __restrict__ Vt) {
  __shared__ __align__(16) unsigned short Ab[3][128 * 32];
  __shared__ __align__(16) unsigned short Bb[3][128 * 32];

  const int bid = blockIdx.x;
  const int t = threadIdx.x;
  const int lane = t & 63;
  const int w = t >> 6;
  const int wm = w & 1, wn = w >> 1;

  const bool is_vt = bid >= 1536;
  const unsigned short* srcA;
  const unsigned short* srcB;
  int m0, n0, z = 0;
  if (!is_vt) {
    z = bid / 768;
    const int r = bid - z * 768;
    m0 = (r & 127) * 128;        // r%128
    n0 = (r >> 7) * 128;         // r/128 in 0..5
    srcA = hsb;
    srcB = z ? Wkb : Wqb;
  } else {
    const int r = bid - 1536;
    const int mx = r % 6;
    m0 = mx * 128;               // o
    n0 = (r / 6) * 128;          // m = b*4096+s
    srcA = Wvb;
    srcB = hsb;
  }

  f32x4 acc[4][4] = {};

  auto issueT = [&](const unsigned short* src, int base, int kk, unsigned short* dst) {
#pragma unroll
    for (int r = 0; r < 2; r++) {
      int u = r * 256 + t;
      int o = u >> 2, cc = u & 3;
      int c = cc ^ ((o >> 1) & 3);
      gll16(src + (size_t)(base + o) * 768 + kk + c * 8, dst + u * 8);
    }
  };

  // prologue: stages 0 and 1 in flight; drain stage 0, keep stage 1.
  issueT(srcA, m0, 0, Ab[0]);
  issueT(srcB, n0, 0, Bb[0]);
  issueT(srcA, m0, 32, Ab[1]);
  issueT(srcB, n0, 32, Bb[1]);
  ASM_WAITV4();
  ASM_BAR();

  for (int k = 0; k < 24; k++) {
    const int buf = k % 3;
    if (k < 22) {
      const int nb = (k + 2) % 3;
      issueT(srcA, m0, (k + 2) * 32, Ab[nb]);
      issueT(srcB, n0, (k + 2) * 32, Bb[nb]);
    }
    bf16x8 af[4], bfr[4];
#pragma unroll
    for (int mt = 0; mt < 4; mt++) {
      int row = wm * 64 + mt * 16 + (lane & 15);
      int cc = (lane >> 4) ^ ((row >> 1) & 3);
      af[mt] = *(const bf16x8*)(&Ab[buf][row * 32 + cc * 8]);
    }
#pragma unroll
    for (int nt = 0; nt < 4; nt++) {
      int row = wn * 64 + nt * 16 + (lane & 15);
      int cc = (lane >> 4) ^ ((row >> 1) & 3);
      bfr[nt] = *(const bf16x8*)(&Bb[buf][row * 32 + cc * 8]);
    }
#pragma unroll
    for (int mt = 0; mt < 4; mt++)
#pragma unroll
      for (int nt = 0; nt < 4; nt++) acc[mt][nt] = MFMA16(af[mt], bfr[nt], acc[mt][nt]);
    // drain stage(k+1) (oldest 4), keep stage(k+2) in flight across barrier.
    if (k < 22) {
      ASM_WAITV4();
    } else {
      ASM_WAITV0();
    }
    ASM_BAR();
  }

  if (!is_vt) {
    const float* bias = z ? bk : bq;
    unsigned short* out = z ? Kb : Qb;
#pragma unroll
    for (int nt = 0; nt < 4; nt++) {
      int col = n0 + wn * 64 + nt * 16 + (lane & 15);
      float bv_ = bias[col];
#pragma unroll
      for (int mt = 0; mt < 4; mt++) {
#pragma unroll
        for (int i = 0; i < 4; i++) {
          int row = m0 + wm * 64 + mt * 16 + (lane >> 4) * 4 + i;
          out[(size_t)row * 768 + col] = f2bf(acc[mt][nt][i] + bv_);
        }
      }
    }
  } else {
#pragma unroll
    for (int mt = 0; mt < 4; mt++) {
#pragma unroll
      for (int i = 0; i < 4; i++) {
        int row_o = m0 + wm * 64 + mt * 16 + (lane >> 4) * 4 + i;
        float bb = bv[row_o];
#pragma unroll
        for (int nt = 0; nt < 4; nt++) {
          int mcol = n0 + wn * 64 + nt * 16 + (lane & 15);
          int bat = mcol >> 12, s = mcol & 4095;
          Vt[(size_t)bat * 768 * 4096 + (size_t)row_o * 4096 + s] = f2bf(acc[mt][nt][i] + bb);
        }
      }
    }
  }
}

// ---------------- flash attention (v8 = R11-verified) ----------------
// 512 thr / 8 waves. QK: rg = w&1 (32 q-rows, 32x32 MFMA), hg = w>>1 (192-c
// slice). PV: mt2 = w&1 (2 row-tiles), dg = w>>1 (192-d quarter).
// Denominator: per-thread f32 register accumulation over j (4 adds/iter),
// single cross-column shuffle reduce after the loop -> st_l (written once).
// LDS = kbuf 48 + vbuf 48 + sx 32 + pbuf 4 + kb_lds 16 ~ 148 KB.
__global__ __launch_bounds__(512, 2) void flash_kernel(const unsigned short* __restrict__ Qb,
                                                       const unsigned short* __restrict__ Kb,
                                                       const unsigned short* __restrict__ Vt,
                                                       const float* __restrict__ KB,
                                                       float* __restrict__ out) {
  __shared__ __align__(16) unsigned short kbuf[32 * 768];   // 48 KB
  __shared__ __align__(16) unsigned short vbuf[768 * 32];   // 48 KB
  __shared__ __align__(16) unsigned short pbuf[4 * 64 * 8]; // 4 KB
  __shared__ __align__(16) float sx[4 * 2 * 64 * 16];       // 32 KB, XOR-swizzled chunks
  __shared__ __align__(16) float kb_lds[4096];              // 16 KB
  __shared__ float st_l[64];

  const int t = threadIdx.x;
  const int lane = t & 63;
  const int w = t >> 6;
  const int rg = w & 1, hg = w >> 1;   // QK roles
  const int mt2 = w & 1, dg = w >> 1;  // PV roles
  const int flat = blockIdx.x;
  const int b = flat & 3, qt = flat >> 2;
  const int q0 = qt * 64;

  const unsigned short* Qg = Qb + (size_t)b * 4096 * 768;
  const unsigned short* Kg = Kb + (size_t)b * 4096 * 768;
  const unsigned short* Vg = Vt + (size_t)b * 768 * 4096;
  const float* KBb = KB + b * 4096;

  // Q A-frags for 32x32x16: row = lane&31, k = (lane>>5)*8 + 0..7
  bf16x8 qf[12];
  {
    const unsigned short* qp =
        Qg + (size_t)(q0 + rg * 32 + (lane & 31)) * 768 + hg * 192 + (lane >> 5) * 8;
#pragma unroll
    for (int c = 0; c < 12; c++) qf[c] = *(const bf16x8*)(qp + c * 16);
  }
  // KB preload into LDS (512 thr x 8 floats)
#pragma unroll
  for (int r = 0; r < 2; r++) {
    int i = t * 8 + r * 4;
    *(float4*)(kb_lds + i) = *(const float4*)(KBb + i);
  }

  // QK kbuf read offsets (shorts), loop-invariant.
  int kidx[12];
  {
    const int key = lane & 31, l5 = lane >> 5, sw = (key >> 1) & 3;
#pragma unroll
    for (int c = 0; c < 12; c++) {
      int g = hg * 24 + c * 2 + l5;
      kidx[c] = ((g >> 2) * 128 + key * 4 + ((g & 3) ^ sw)) * 8;
    }
  }
  // PV vbuf base
  int vbase;
  {
    int d0 = dg * 192 + (lane & 15);
    vbase = (d0 * 4 + ((lane >> 4) ^ ((d0 >> 1) & 3))) * 8;
  }
  // pbuf A-frag read offsets (perm: r ^ 2g ^ ((r>>2)&1))
  int pidx0, pidx1;
  {
    int g2 = lane >> 4;
    int r0 = mt2 * 32 + (lane & 15);
    int r1 = r0 + 16;
    pidx0 = (g2 * 64 + (r0 ^ (g2 * 2) ^ ((r0 >> 2) & 1))) * 8;
    pidx1 = (g2 * 64 + (r1 ^ (g2 * 2) ^ ((r1 >> 2) & 1))) * 8;
  }
  // softmax redistribution constants
  const int s_rg = t >> 8, s_q = (t >> 6) & 3, s_l = t & 63;
  const int col = s_l & 31;
  const int row_b = s_rg * 32 + 8 * s_q + 4 * (s_l >> 5);
  int pslot[4];
#pragma unroll
  for (int jj = 0; jj < 4; jj++) {
    int rw = row_b + jj;
    pslot[jj] = ((col >> 3) * 64 + (rw ^ ((col >> 3) * 2) ^ ((rw >> 2) & 1))) * 8 + (col & 7);
  }
  // sx: plane hg (2048 dwords), row r*16, chunk XOR-swizzled by (r>>1)&3
  float* sxw = sx + hg * 2048 + (rg * 64 + lane) * 16;
  const int wswz = (lane >> 1) & 3;
  const float* sxr = sx + (s_rg * 64 + s_l) * 16 + (s_q ^ ((s_l >> 1) & 3)) * 4;

  f32x4 oacc[24] = {};
  float racc0 = 0.0f, racc1 = 0.0f, racc2 = 0.0f, racc3 = 0.0f;  // f32 denom partials

  auto issueK = [&](int j) {
#pragma unroll
    for (int r = 0; r < 6; r++) {
      int u = r * 512 + t;
      int ks = u >> 7, rem = u & 127, key = rem >> 2, cs = rem & 3;
      int c = cs ^ ((key >> 1) & 3);
      gll16(Kg + (size_t)(j * 32 + key) * 768 + ks * 32 + c * 8, &kbuf[u * 8]);
    }
  };
  auto issueV = [&](int j) {
#pragma unroll
    for (int r = 0; r < 6; r++) {
      int u = r * 512 + t;
      int d = u >> 2, cs = u & 3;
      int c = cs ^ ((d >> 1) & 3);
      gll16(Vg + (size_t)d * 4096 + j * 32 + c * 8, &vbuf[u * 8]);
    }
  };

  issueK(0);
  ASM_WAITV0();  // K(0) drained (ours); barrier makes all waves' K(0) visible
  ASM_BAR();

  for (int j = 0; j < 128; j++) {
    // entry: queue empty; kbuf holds K(j), fully visible
    issueV(j);  // queue [V(j):6]; vbuf free (all waves past PV(j-1) drain at (A))
    // ---- QK ----
    f32x16 s = {};
#pragma unroll
    for (int c = 0; c < 12; c++) {
      bf16x8 kf = *(const bf16x8*)(kbuf + kidx[c]);
      s = MFMA32(qf[c], kf, s);
    }
#pragma unroll
    for (int i = 0; i < 4; i++) {
      *(float4*)(sxw + (i ^ wswz) * 4) =
          make_float4(s[i * 4], s[i * 4 + 1], s[i * 4 + 2], s[i * 4 + 3]);
    }
    ASM_WAITL0();
    ASM_BAR();  // (B): sx visible; kbuf reads done by all waves
    if (j < 127) issueK(j + 1);  // queue [V(j):6, K(j+1):6]
    // ---- softmax: 512 threads x 4 elements, exp2, reg-accumulated denom ----
    {
      float4 a0 = *(const float4*)(sxr);
      float4 a1 = *(const float4*)(sxr + 2048);
      float4 a2 = *(const float4*)(sxr + 4096);
      float4 a3 = *(const float4*)(sxr + 6144);
      float kbias = kb_lds[j * 32 + col];
      float e0 = __builtin_amdgcn_exp2f(fmaf(a0.x + a1.x + a2.x + a3.x, SCALE_L2E, kbias));
      float e1 = __builtin_amdgcn_exp2f(fmaf(a0.y + a1.y + a2.y + a3.y, SCALE_L2E, kbias));
      float e2 = __builtin_amdgcn_exp2f(fmaf(a0.z + a1.z + a2.z + a3.z, SCALE_L2E, kbias));
      float e3 = __builtin_amdgcn_exp2f(fmaf(a0.w + a1.w + a2.w + a3.w, SCALE_L2E, kbias));
      pbuf[pslot[0]] = f2bf(e0);
      pbuf[pslot[1]] = f2bf(e1);
      pbuf[pslot[2]] = f2bf(e2);
      pbuf[pslot[3]] = f2bf(e3);
      racc0 += e0;
      racc1 += e1;
      racc2 += e2;
      racc3 += e3;
    }
    ASM_WAITL0();
    // (C) drain: normal iters have queue [V(j):6, K(j+1):6] -> vmcnt(6)
    // drains V. Final iter has only [V(127):6] -> must drain fully.
    if (j < 127) {
      ASM_WAITV6();
    } else {
      ASM_WAITV0();
    }
    ASM_BAR();     // (C): pbuf visible; all waves' V(j) drained -> vbuf valid
    // ---- PV ----
    {
      bf16x8 pf0 = *(const bf16x8*)(pbuf + pidx0);
      bf16x8 pf1 = *(const bf16x8*)(pbuf + pidx1);
#pragma unroll
      for (int dt = 0; dt < 12; dt++) {
        bf16x8 vf = *(const bf16x8*)(vbuf + vbase + dt * 512);
        oacc[dt] = MFMA16(pf0, vf, oacc[dt]);
        oacc[12 + dt] = MFMA16(pf1, vf, oacc[12 + dt]);
      }
    }
    ASM_WAITV0();  // K(j+1) drained (ours)
    ASM_BAR();     // (A): all waves' K(j+1) visible; vbuf/pbuf reads done
  }
  // ---- final denominator reduction (once): sum racc across 32 cols ----
#pragma unroll
  for (int m = 1; m < 32; m <<= 1) {
    racc0 += __shfl_xor(racc0, m, 32);
    racc1 += __shfl_xor(racc1, m, 32);
    racc2 += __shfl_xor(racc2, m, 32);
    racc3 += __shfl_xor(racc3, m, 32);
  }
  if ((s_l & 31) == 0) {
    st_l[row_b] = racc0;
    st_l[row_b + 1] = racc1;
    st_l[row_b + 2] = racc2;
    st_l[row_b + 3] = racc3;
  }
  __syncthreads();
  // ---- epilogue ----
#pragma unroll
  for (int pt = 0; pt < 2; pt++) {
    int rb = mt2 * 32 + pt * 16 + (lane >> 4) * 4;
    float l0 = 1.0f / st_l[rb], l1 = 1.0f / st_l[rb + 1];
    float l2 = 1.0f / st_l[rb + 2], l3 = 1.0f / st_l[rb + 3];
#pragma unroll
    for (int dt = 0; dt < 12; dt++) {
      int d = dg * 192 + dt * 16 + (lane & 15);
      size_t base = ((size_t)(b * 4096 + q0 + rb)) * 768 + d;
      out[base] = oacc[pt * 12 + dt][0] * l0;
      out[base + 768] = oacc[pt * 12 + dt][1] * l1;
      out[base + 2 * 768] = oacc[pt * 12 + dt][2] * l2;
      out[base + 3 * 768] = oacc[pt * 12 + dt][3] * l3;
    }
  }
}

extern "C" void kernel_launch(void* const* d_in, const int* in_sizes, int n_in, void* d_out,
                              int out_size, void* d_ws, size_t ws_size, hipStream_t stream) {
  const float* hs = (const float*)d_in[0];
  const float* mask = (const float*)d_in[1];
  const int* ep = (const int*)d_in[2];
  const float* Wq = (const float*)d_in[3];
  const float* bq = (const float*)d_in[4];
  const float* Wk = (const float*)d_in[5];
  const float* bk = (const float*)d_in[6];
  const float* Wv = (const float*)d_in[7];
  const float* bv = (const float*)d_in[8];
  float* outp = (float*)d_out;

  char* ws = (char*)d_ws;
  unsigned short* Qb = (unsigned short*)(ws);
  unsigned short* Kb = (unsigned short*)(ws + 25165824);
  unsigned short* Vt = (unsigned short*)(ws + 50331648);
  unsigned short* Wqb = (unsigned short*)(ws + 75497472);
  unsigned short* Wkb = (unsigned short*)(ws + 76677120);
  unsigned short* Wvb = (unsigned short*)(ws + 77856768);
  float* KBp = (float*)(ws + 79036416);
  unsigned short* Hsb = (unsigned short*)(ws + 79101952);  // 16384x768 bf16, 24 MB

  prep_kernel<<<HS_BLOCKS + W_BLOCKS + KB_BLOCKS, 256, 0, stream>>>(
      hs, Hsb, Wq, Wk, Wv, Wqb, Wkb, Wvb, mask, ep, KBp);
  gemm_qkv_kernel<<<2304, 256, 0, stream>>>(Hsb, Wqb, Wkb, Wvb, bq, bk, bv, Qb, Kb, Vt);
  flash_kernel<<<256, 512, 0, stream>>>(Qb, Kb, Vt, KBp, outp);
}

// Round 12
// 473.825 us; speedup vs baseline: 1.4619x; 1.0095x over previous
//
#include <hip/hip_runtime.h>

// EntityAwareAttention on MI355X (gfx950), bf16 MFMA pipeline.
// R15 = R14 + (1) Vt-section XCD swizzle + (2) flash kbias hoist.
// (1) T1: Vt blocks sharing an hs n-panel (196 KB) were consecutive bids ->
//     spread over 6 XCDs -> ~6x panel refetch. Remap d=(n&7)+8*((n>>3)*6+m)
//     (bijective; inverse n=((r>>3)/6)*8+(r&7), m=(r>>3)%6): same-n blocks
//     share d%8 -> one XCD; 16 panels x 196 KB = 3.1 MB fits 4 MB XCD-L2.
//     QK section audited: A-panel sharers already same-XCD (bid%8 == m%8).
// (2) kb_lds read moved from the (B)->(C) critical softmax section into the
//     QK phase (pure reorder; drained by the existing lgkm wait at (B)).
// Structural ledger (constraint written R11-R14): flash is DS/barrier-
// serialized at 1 block/CU; 2-blocks/CU requires KVBLK=16 + 16x16-MFMA
// rewrite whose per-thread state sits at the 128-VGPR occupancy step (m69)
// -- negative EV after R12/R13. Gemm z-merge doubles acc -> m132 trap.
// Flash queue discipline per wave/iter (R7-verified):
//   [entry: queue empty] issueV(j):6 -> kbias -> QK -> sx -> lgkm,BAR(B)
//   -> issueK(j+1):6 -> softmax -> lgkm,vmcnt(6|0),BAR(C)
//   -> PV -> vmcnt(0)[K drained],BAR(A)

typedef short bf16x8 __attribute__((ext_vector_type(8)));
typedef float f32x4 __attribute__((ext_vector_type(4)));
typedef float f32x16 __attribute__((ext_vector_type(16)));

#define MFMA16(a, b, c) __builtin_amdgcn_mfma_f32_16x16x32_bf16(a, b, c, 0, 0, 0)
#define MFMA32(a, b, c) __builtin_amdgcn_mfma_f32_32x32x16_bf16(a, b, c, 0, 0, 0)

#define ASM_BAR() asm volatile("s_barrier" ::: "memory")
#define ASM_WAITV0() asm volatile("s_waitcnt vmcnt(0)" ::: "memory")
#define ASM_WAITV4() asm volatile("s_waitcnt vmcnt(4)" ::: "memory")
#define ASM_WAITV6() asm volatile("s_waitcnt vmcnt(6)" ::: "memory")
#define ASM_WAITL0() asm volatile("s_waitcnt lgkmcnt(0)" ::: "memory")

__device__ __forceinline__ unsigned short f2bf(float f) {
  unsigned u = __float_as_uint(f);
  u = u + 0x7FFFu + ((u >> 16) & 1u);  // RNE
  return (unsigned short)(u >> 16);
}

__device__ __forceinline__ void gll16(const void* g, void* l) {
  __builtin_amdgcn_global_load_lds(
      (const __attribute__((address_space(1))) unsigned int*)g,
      (__attribute__((address_space(3))) unsigned int*)l, 16, 0, 0);
}

// 1/sqrt(768) * log2(e): softmax computed as exp2((qk)*SCALE_L2E + kb*log2e)
#define SCALE_L2E 0.05205877316f
#define LOG2E 1.4426950408889634f

// ---------------- fused prep: hs->bf16, W->bf16, key-bias table ----------------
#define HS_BLOCKS 12288
#define W_BLOCKS 1728
#define KB_BLOCKS 64
__global__ void prep_kernel(const float* __restrict__ hs, unsigned short* __restrict__ ohs,
                            const float* __restrict__ w0, const float* __restrict__ w1,
                            const float* __restrict__ w2, unsigned short* __restrict__ o0,
                            unsigned short* __restrict__ o1, unsigned short* __restrict__ o2,
                            const float* __restrict__ mask, const int* __restrict__ ep,
                            float* __restrict__ kb) {
  __shared__ int eps[64];
  const int bid = blockIdx.x;
  const int t = threadIdx.x;
  if (bid < HS_BLOCKS) {
    const int i = (bid * 256 + t) * 4;
    float4 v = *(const float4*)(hs + i);
    *(ushort4*)(ohs + i) = make_ushort4(f2bf(v.x), f2bf(v.y), f2bf(v.z), f2bf(v.w));
  } else if (bid < HS_BLOCKS + W_BLOCKS) {
    const int wb = bid - HS_BLOCKS;
    const int which = wb / 576;
    const float* s = which == 0 ? w0 : (which == 1 ? w1 : w2);
    unsigned short* d = which == 0 ? o0 : (which == 1 ? o1 : o2);
    const int i = ((wb - which * 576) * 256 + t) * 4;
    float4 v = *(const float4*)(s + i);
    *(ushort4*)(d + i) = make_ushort4(f2bf(v.x), f2bf(v.y), f2bf(v.z), f2bf(v.w));
  } else {
    const int s = (bid - HS_BLOCKS - W_BLOCKS) * 256 + t;  // 0..16383
    const int b = s >> 12;                                 // block spans one batch
    if (t < 64) eps[t] = ep[b * 64 + t];
    __syncthreads();
    const int sp = s & 4095;
    float cnt = 0.0f;
#pragma unroll 8
    for (int e = 0; e < 64; e++) cnt += (eps[e] == sp) ? 1.0f : 0.0f;
    kb[s] = (1.0f - mask[s]) * (-10000.0f * LOG2E) + cnt * LOG2E;
  }
}

// ---------------- fused GEMM: Q,K = hs@W^T+b (bids 0..1535), V^T (1536..2303) --
__global__ __launch_bounds__(256, 3) void gemm_qkv_kernel(
    const unsigned short* __restrict__ hsb, const unsigned short* __restrict__ Wqb,
    const unsigned short* __restrict__ Wkb, const unsigned short* __restrict__ Wvb,
    const float* __restrict__ bq, const float* __restrict__ bk, const float* __restrict__ bv,
    unsigned short* __restrict__ Qb, unsigned short* __restrict__ Kb,
    unsigned short* __restrict__ Vt) {
  __shared__ __align__(16) unsigned short Ab[3][128 * 32];
  __shared__ __align__(16) unsigned short Bb[3][128 * 32];

  const int bid = blockIdx.x;
  const int t = threadIdx.x;
  const int lane = t & 63;
  const int w = t >> 6;
  const int wm = w & 1, wn = w >> 1;

  const bool is_vt = bid >= 1536;
  const unsigned short* srcA;
  const unsigned short* srcB;
  int m0, n0, z = 0;
  if (!is_vt) {
    z = bid / 768;
    const int r = bid - z * 768;
    m0 = (r & 127) * 128;        // r%128 ; A-panel sharers: bid%8==m%8 (same XCD)
    n0 = (r >> 7) * 128;         // r/128 in 0..5
    srcA = hsb;
    srcB = z ? Wkb : Wqb;
  } else {
    // XCD swizzle (T1): d = (n&7) + 8*((n>>3)*6 + m); inverse below.
    // Same-n (shared hs panel) blocks have equal d%8 -> same XCD L2.
    const int r = bid - 1536;
    const int n = ((r >> 3) / 6) * 8 + (r & 7);  // n-tile 0..127
    const int mx = (r >> 3) % 6;                 // o-tile 0..5
    m0 = mx * 128;               // o
    n0 = n * 128;                // m = b*4096+s
    srcA = Wvb;
    srcB = hsb;
  }

  f32x4 acc[4][4] = {};

  auto issueT = [&](const unsigned short* src, int base, int kk, unsigned short* dst) {
#pragma unroll
    for (int r = 0; r < 2; r++) {
      int u = r * 256 + t;
      int o = u >> 2, cc = u & 3;
      int c = cc ^ ((o >> 1) & 3);
      gll16(src + (size_t)(base + o) * 768 + kk + c * 8, dst + u * 8);
    }
  };

  // prologue: stages 0 and 1 in flight; drain stage 0, keep stage 1.
  issueT(srcA, m0, 0, Ab[0]);
  issueT(srcB, n0, 0, Bb[0]);
  issueT(srcA, m0, 32, Ab[1]);
  issueT(srcB, n0, 32, Bb[1]);
  ASM_WAITV4();
  ASM_BAR();

  for (int k = 0; k < 24; k++) {
    const int buf = k % 3;
    if (k < 22) {
      const int nb = (k + 2) % 3;
      issueT(srcA, m0, (k + 2) * 32, Ab[nb]);
      issueT(srcB, n0, (k + 2) * 32, Bb[nb]);
    }
    bf16x8 af[4], bfr[4];
#pragma unroll
    for (int mt = 0; mt < 4; mt++) {
      int row = wm * 64 + mt * 16 + (lane & 15);
      int cc = (lane >> 4) ^ ((row >> 1) & 3);
      af[mt] = *(const bf16x8*)(&Ab[buf][row * 32 + cc * 8]);
    }
#pragma unroll
    for (int nt = 0; nt < 4; nt++) {
      int row = wn * 64 + nt * 16 + (lane & 15);
      int cc = (lane >> 4) ^ ((row >> 1) & 3);
      bfr[nt] = *(const bf16x8*)(&Bb[buf][row * 32 + cc * 8]);
    }
#pragma unroll
    for (int mt = 0; mt < 4; mt++)
#pragma unroll
      for (int nt = 0; nt < 4; nt++) acc[mt][nt] = MFMA16(af[mt], bfr[nt], acc[mt][nt]);
    // drain stage(k+1) (oldest 4), keep stage(k+2) in flight across barrier.
    if (k < 22) {
      ASM_WAITV4();
    } else {
      ASM_WAITV0();
    }
    ASM_BAR();
  }

  if (!is_vt) {
    const float* bias = z ? bk : bq;
    unsigned short* out = z ? Kb : Qb;
#pragma unroll
    for (int nt = 0; nt < 4; nt++) {
      int col = n0 + wn * 64 + nt * 16 + (lane & 15);
      float bv_ = bias[col];
#pragma unroll
      for (int mt = 0; mt < 4; mt++) {
#pragma unroll
        for (int i = 0; i < 4; i++) {
          int row = m0 + wm * 64 + mt * 16 + (lane >> 4) * 4 + i;
          out[(size_t)row * 768 + col] = f2bf(acc[mt][nt][i] + bv_);
        }
      }
    }
  } else {
#pragma unroll
    for (int mt = 0; mt < 4; mt++) {
#pragma unroll
      for (int i = 0; i < 4; i++) {
        int row_o = m0 + wm * 64 + mt * 16 + (lane >> 4) * 4 + i;
        float bb = bv[row_o];
#pragma unroll
        for (int nt = 0; nt < 4; nt++) {
          int mcol = n0 + wn * 64 + nt * 16 + (lane & 15);
          int bat = mcol >> 12, s = mcol & 4095;
          Vt[(size_t)bat * 768 * 4096 + (size_t)row_o * 4096 + s] = f2bf(acc[mt][nt][i] + bb);
        }
      }
    }
  }
}

// ---------------- flash attention (v8 + kbias hoist) ----------------
// 512 thr / 8 waves. QK: rg = w&1 (32 q-rows, 32x32 MFMA), hg = w>>1 (192-c
// slice). PV: mt2 = w&1 (2 row-tiles), dg = w>>1 (192-d quarter).
// Denominator: per-thread f32 register accumulation over j (4 adds/iter),
// single cross-column shuffle reduce after the loop -> st_l (written once).
// LDS = kbuf 48 + vbuf 48 + sx 32 + pbuf 4 + kb_lds 16 ~ 148 KB.
__global__ __launch_bounds__(512, 2) void flash_kernel(const unsigned short* __restrict__ Qb,
                                                       const unsigned short* __restrict__ Kb,
                                                       const unsigned short* __restrict__ Vt,
                                                       const float* __restrict__ KB,
                                                       float* __restrict__ out) {
  __shared__ __align__(16) unsigned short kbuf[32 * 768];   // 48 KB
  __shared__ __align__(16) unsigned short vbuf[768 * 32];   // 48 KB
  __shared__ __align__(16) unsigned short pbuf[4 * 64 * 8]; // 4 KB
  __shared__ __align__(16) float sx[4 * 2 * 64 * 16];       // 32 KB, XOR-swizzled chunks
  __shared__ __align__(16) float kb_lds[4096];              // 16 KB
  __shared__ float st_l[64];

  const int t = threadIdx.x;
  const int lane = t & 63;
  const int w = t >> 6;
  const int rg = w & 1, hg = w >> 1;   // QK roles
  const int mt2 = w & 1, dg = w >> 1;  // PV roles
  const int flat = blockIdx.x;
  const int b = flat & 3, qt = flat >> 2;
  const int q0 = qt * 64;

  const unsigned short* Qg = Qb + (size_t)b * 4096 * 768;
  const unsigned short* Kg = Kb + (size_t)b * 4096 * 768;
  const unsigned short* Vg = Vt + (size_t)b * 768 * 4096;
  const float* KBb = KB + b * 4096;

  // Q A-frags for 32x32x16: row = lane&31, k = (lane>>5)*8 + 0..7
  bf16x8 qf[12];
  {
    const unsigned short* qp =
        Qg + (size_t)(q0 + rg * 32 + (lane & 31)) * 768 + hg * 192 + (lane >> 5) * 8;
#pragma unroll
    for (int c = 0; c < 12; c++) qf[c] = *(const bf16x8*)(qp + c * 16);
  }
  // KB preload into LDS (512 thr x 8 floats)
#pragma unroll
  for (int r = 0; r < 2; r++) {
    int i = t * 8 + r * 4;
    *(float4*)(kb_lds + i) = *(const float4*)(KBb + i);
  }

  // QK kbuf read offsets (shorts), loop-invariant.
  int kidx[12];
  {
    const int key = lane & 31, l5 = lane >> 5, sw = (key >> 1) & 3;
#pragma unroll
    for (int c = 0; c < 12; c++) {
      int g = hg * 24 + c * 2 + l5;
      kidx[c] = ((g >> 2) * 128 + key * 4 + ((g & 3) ^ sw)) * 8;
    }
  }
  // PV vbuf base
  int vbase;
  {
    int d0 = dg * 192 + (lane & 15);
    vbase = (d0 * 4 + ((lane >> 4) ^ ((d0 >> 1) & 3))) * 8;
  }
  // pbuf A-frag read offsets (perm: r ^ 2g ^ ((r>>2)&1))
  int pidx0, pidx1;
  {
    int g2 = lane >> 4;
    int r0 = mt2 * 32 + (lane & 15);
    int r1 = r0 + 16;
    pidx0 = (g2 * 64 + (r0 ^ (g2 * 2) ^ ((r0 >> 2) & 1))) * 8;
    pidx1 = (g2 * 64 + (r1 ^ (g2 * 2) ^ ((r1 >> 2) & 1))) * 8;
  }
  // softmax redistribution constants
  const int s_rg = t >> 8, s_q = (t >> 6) & 3, s_l = t & 63;
  const int col = s_l & 31;
  const int row_b = s_rg * 32 + 8 * s_q + 4 * (s_l >> 5);
  int pslot[4];
#pragma unroll
  for (int jj = 0; jj < 4; jj++) {
    int rw = row_b + jj;
    pslot[jj] = ((col >> 3) * 64 + (rw ^ ((col >> 3) * 2) ^ ((rw >> 2) & 1))) * 8 + (col & 7);
  }
  // sx: plane hg (2048 dwords), row r*16, chunk XOR-swizzled by (r>>1)&3
  float* sxw = sx + hg * 2048 + (rg * 64 + lane) * 16;
  const int wswz = (lane >> 1) & 3;
  const float* sxr = sx + (s_rg * 64 + s_l) * 16 + (s_q ^ ((s_l >> 1) & 3)) * 4;

  f32x4 oacc[24] = {};
  float racc0 = 0.0f, racc1 = 0.0f, racc2 = 0.0f, racc3 = 0.0f;  // f32 denom partials

  auto issueK = [&](int j) {
#pragma unroll
    for (int r = 0; r < 6; r++) {
      int u = r * 512 + t;
      int ks = u >> 7, rem = u & 127, key = rem >> 2, cs = rem & 3;
      int c = cs ^ ((key >> 1) & 3);
      gll16(Kg + (size_t)(j * 32 + key) * 768 + ks * 32 + c * 8, &kbuf[u * 8]);
    }
  };
  auto issueV = [&](int j) {
#pragma unroll
    for (int r = 0; r < 6; r++) {
      int u = r * 512 + t;
      int d = u >> 2, cs = u & 3;
      int c = cs ^ ((d >> 1) & 3);
      gll16(Vg + (size_t)d * 4096 + j * 32 + c * 8, &vbuf[u * 8]);
    }
  };

  issueK(0);
  ASM_WAITV0();  // K(0) drained (ours); barrier makes all waves' K(0) visible
  ASM_BAR();

  for (int j = 0; j < 128; j++) {
    // entry: queue empty; kbuf holds K(j), fully visible
    issueV(j);  // queue [V(j):6]; vbuf free (all waves past PV(j-1) drain at (A))
    // kbias hoist: issue the LDS read in the QK phase so its latency is off
    // the (B)->(C) critical softmax section (drained by lgkm before BAR(B)).
    const float kbias = kb_lds[j * 32 + col];
    // ---- QK ----
    f32x16 s = {};
#pragma unroll
    for (int c = 0; c < 12; c++) {
      bf16x8 kf = *(const bf16x8*)(kbuf + kidx[c]);
      s = MFMA32(qf[c], kf, s);
    }
#pragma unroll
    for (int i = 0; i < 4; i++) {
      *(float4*)(sxw + (i ^ wswz) * 4) =
          make_float4(s[i * 4], s[i * 4 + 1], s[i * 4 + 2], s[i * 4 + 3]);
    }
    ASM_WAITL0();
    ASM_BAR();  // (B): sx visible; kbuf reads done by all waves
    if (j < 127) issueK(j + 1);  // queue [V(j):6, K(j+1):6]
    // ---- softmax: 512 threads x 4 elements, exp2, reg-accumulated denom ----
    {
      float4 a0 = *(const float4*)(sxr);
      float4 a1 = *(const float4*)(sxr + 2048);
      float4 a2 = *(const float4*)(sxr + 4096);
      float4 a3 = *(const float4*)(sxr + 6144);
      float e0 = __builtin_amdgcn_exp2f(fmaf(a0.x + a1.x + a2.x + a3.x, SCALE_L2E, kbias));
      float e1 = __builtin_amdgcn_exp2f(fmaf(a0.y + a1.y + a2.y + a3.y, SCALE_L2E, kbias));
      float e2 = __builtin_amdgcn_exp2f(fmaf(a0.z + a1.z + a2.z + a3.z, SCALE_L2E, kbias));
      float e3 = __builtin_amdgcn_exp2f(fmaf(a0.w + a1.w + a2.w + a3.w, SCALE_L2E, kbias));
      pbuf[pslot[0]] = f2bf(e0);
      pbuf[pslot[1]] = f2bf(e1);
      pbuf[pslot[2]] = f2bf(e2);
      pbuf[pslot[3]] = f2bf(e3);
      racc0 += e0;
      racc1 += e1;
      racc2 += e2;
      racc3 += e3;
    }
    ASM_WAITL0();
    // (C) drain: normal iters have queue [V(j):6, K(j+1):6] -> vmcnt(6)
    // drains V. Final iter has only [V(127):6] -> must drain fully.
    if (j < 127) {
      ASM_WAITV6();
    } else {
      ASM_WAITV0();
    }
    ASM_BAR();     // (C): pbuf visible; all waves' V(j) drained -> vbuf valid
    // ---- PV ----
    {
      bf16x8 pf0 = *(const bf16x8*)(pbuf + pidx0);
      bf16x8 pf1 = *(const bf16x8*)(pbuf + pidx1);
#pragma unroll
      for (int dt = 0; dt < 12; dt++) {
        bf16x8 vf = *(const bf16x8*)(vbuf + vbase + dt * 512);
        oacc[dt] = MFMA16(pf0, vf, oacc[dt]);
        oacc[12 + dt] = MFMA16(pf1, vf, oacc[12 + dt]);
      }
    }
    ASM_WAITV0();  // K(j+1) drained (ours)
    ASM_BAR();     // (A): all waves' K(j+1) visible; vbuf/pbuf reads done
  }
  // ---- final denominator reduction (once): sum racc across 32 cols ----
#pragma unroll
  for (int m = 1; m < 32; m <<= 1) {
    racc0 += __shfl_xor(racc0, m, 32);
    racc1 += __shfl_xor(racc1, m, 32);
    racc2 += __shfl_xor(racc2, m, 32);
    racc3 += __shfl_xor(racc3, m, 32);
  }
  if ((s_l & 31) == 0) {
    st_l[row_b] = racc0;
    st_l[row_b + 1] = racc1;
    st_l[row_b + 2] = racc2;
    st_l[row_b + 3] = racc3;
  }
  __syncthreads();
  // ---- epilogue ----
#pragma unroll
  for (int pt = 0; pt < 2; pt++) {
    int rb = mt2 * 32 + pt * 16 + (lane >> 4) * 4;
    float l0 = 1.0f / st_l[rb], l1 = 1.0f / st_l[rb + 1];
    float l2 = 1.0f / st_l[rb + 2], l3 = 1.0f / st_l[rb + 3];
#pragma unroll
    for (int dt = 0; dt < 12; dt++) {
      int d = dg * 192 + dt * 16 + (lane & 15);
      size_t base = ((size_t)(b * 4096 + q0 + rb)) * 768 + d;
      out[base] = oacc[pt * 12 + dt][0] * l0;
      out[base + 768] = oacc[pt * 12 + dt][1] * l1;
      out[base + 2 * 768] = oacc[pt * 12 + dt][2] * l2;
      out[base + 3 * 768] = oacc[pt * 12 + dt][3] * l3;
    }
  }
}

extern "C" void kernel_launch(void* const* d_in, const int* in_sizes, int n_in, void* d_out,
                              int out_size, void* d_ws, size_t ws_size, hipStream_t stream) {
  const float* hs = (const float*)d_in[0];
  const float* mask = (const float*)d_in[1];
  const int* ep = (const int*)d_in[2];
  const float* Wq = (const float*)d_in[3];
  const float* bq = (const float*)d_in[4];
  const float* Wk = (const float*)d_in[5];
  const float* bk = (const float*)d_in[6];
  const float* Wv = (const float*)d_in[7];
  const float* bv = (const float*)d_in[8];
  float* outp = (float*)d_out;

  char* ws = (char*)d_ws;
  unsigned short* Qb = (unsigned short*)(ws);
  unsigned short* Kb = (unsigned short*)(ws + 25165824);
  unsigned short* Vt = (unsigned short*)(ws + 50331648);
  unsigned short* Wqb = (unsigned short*)(ws + 75497472);
  unsigned short* Wkb = (unsigned short*)(ws + 76677120);
  unsigned short* Wvb = (unsigned short*)(ws + 77856768);
  float* KBp = (float*)(ws + 79036416);
  unsigned short* Hsb = (unsigned short*)(ws + 79101952);  // 16384x768 bf16, 24 MB

  prep_kernel<<<HS_BLOCKS + W_BLOCKS + KB_BLOCKS, 256, 0, stream>>>(
      hs, Hsb, Wq, Wk, Wv, Wqb, Wkb, Wvb, mask, ep, KBp);
  gemm_qkv_kernel<<<2304, 256, 0, stream>>>(Hsb, Wqb, Wkb, Wvb, bq, bk, bv, Qb, Kb, Vt);
  flash_kernel<<<256, 512, 0, stream>>>(Qb, Kb, Vt, KBp, outp);
}